// Round 3
// baseline (3226.263 us; speedup 1.0000x reference)
//
#include <hip/hip_runtime.h>
#include <cstdint>
#include <cstddef>

#define NLV 12
#define NPL 10000
#define KE 3
#define EPL (NPL * KE)   // 30000 edges per level block
#define NE (11 * EPL)    // 330000
#define NT (NLV * NPL)   // 120000 nodes
#define H 100
#define H2 50
#define FD 4
#define DM 30
#define AP 52            // pre50 row stride (13 float4)
#define TN 20            // nodes per block (500 blocks exactly)
#define YS 400           // Y LDS row stride (dwords)
#define HSS 100          // hs LDS row stride
#define NWS 108          // nwT row stride

__device__ __forceinline__ float sigmoidf_(float x) {
    return 1.0f / (1.0f + __expf(-x));
}
__device__ __forceinline__ float tanhf_(float x) {
    float e = __expf(2.0f * x);
    return 1.0f - 2.0f / (e + 1.0f);
}

// ---------------------------------------------------------------------------
// Weight folding per direction (PER = 28350 outputs):
//  WaT[c*52+k]   = (w2@pw1)[k][c]                        (i < 2500)
//  b2p[c]        = (b2@pw1)[c]                           (2500..2550)
//  W4i[k*400+c]  c=4o+g: g0: pw2[k][o]                   (2550..22550)
//                g1..3: sum_m pw2[k][m]*wh[(g-1)*100+o][m]
//  b4i[c]        g0: pb2[o]; g1: bh[o]+fold+bi[o];       (22550..22950)
//                g2: bh[100+o]+fold+bi[100+o]; g3: bh[200+o]+fold
//  nwT[c*108+k]  = (k<100) ? w1pre[k*50+c] : 0           (22950..28350)
// ---------------------------------------------------------------------------
__global__ void fold_kernel(
    const float* __restrict__ w2F, const float* __restrict__ b2F_,
    const float* __restrict__ pw1F, const float* __restrict__ pw2F,
    const float* __restrict__ pb2F, const float* __restrict__ whF,
    const float* __restrict__ bhF, const float* __restrict__ biF,
    const float* __restrict__ w1pF,
    const float* __restrict__ w2B, const float* __restrict__ b2B_,
    const float* __restrict__ pw1B, const float* __restrict__ pw2B,
    const float* __restrict__ pb2B, const float* __restrict__ whB,
    const float* __restrict__ bhB, const float* __restrict__ biB,
    const float* __restrict__ w1pB,
    float* __restrict__ WaTF, float* __restrict__ b2pF,
    float* __restrict__ W4iF, float* __restrict__ b4iF, float* __restrict__ nwTF,
    float* __restrict__ WaTB, float* __restrict__ b2pB,
    float* __restrict__ W4iB, float* __restrict__ b4iB, float* __restrict__ nwTB)
{
    const int PER = 28350;
    int gid = blockIdx.x * blockDim.x + threadIdx.x;
    if (gid >= 2 * PER) return;
    int dir = gid / PER;
    int i = gid - dir * PER;
    const float* w2  = dir ? w2B  : w2F;
    const float* b2  = dir ? b2B_ : b2F_;
    const float* pw1 = dir ? pw1B : pw1F;
    const float* pw2 = dir ? pw2B : pw2F;
    const float* pb2 = dir ? pb2B : pb2F;
    const float* wh  = dir ? whB  : whF;
    const float* bh  = dir ? bhB  : bhF;
    const float* bi  = dir ? biB  : biF;
    const float* w1p = dir ? w1pB : w1pF;
    float* WaT = dir ? WaTB : WaTF;
    float* b2p = dir ? b2pB : b2pF;
    float* W4i = dir ? W4iB : W4iF;
    float* b4i = dir ? b4iB : b4iF;
    float* nwT = dir ? nwTB : nwTF;

    if (i < 2500) {
        int c = i / 50, k = i - c * 50;
        float s = 0.f;
        for (int m = 0; m < 100; ++m) s += w2[k * 100 + m] * pw1[m * 50 + c];
        WaT[c * AP + k] = s;
    } else if (i < 2550) {
        int c = i - 2500;
        float s = 0.f;
        for (int m = 0; m < 100; ++m) s += b2[m] * pw1[m * 50 + c];
        b2p[c] = s;
        // zero WaT row pads (row c, cols 50..51) so phase B never sees poison
        WaT[c * AP + 50] = 0.f;
        WaT[c * AP + 51] = 0.f;
    } else if (i < 22550) {
        int j = i - 2550;
        int k = j / 400, c = j - k * 400;
        int o = c >> 2, g = c & 3;
        float s;
        if (g == 0) {
            s = pw2[k * 100 + o];
        } else {
            int row = (g - 1) * 100 + o;
            s = 0.f;
            for (int m = 0; m < 100; ++m) s += pw2[k * 100 + m] * wh[row * 100 + m];
        }
        W4i[k * 400 + c] = s;
    } else if (i < 22950) {
        int c = i - 22550;
        int o = c >> 2, g = c & 3;
        float s;
        if (g == 0) {
            s = pb2[o];
        } else {
            int row = (g - 1) * 100 + o;
            s = bh[row];
            for (int m = 0; m < 100; ++m) s += pb2[m] * wh[row * 100 + m];
            if (g == 1) s += bi[o];
            else if (g == 2) s += bi[100 + o];
        }
        b4i[c] = s;
    } else {
        int j = i - 22950;
        int c = j / NWS, k = j - c * NWS;
        nwT[c * NWS + k] = (k < 100) ? w1p[k * 50 + c] : 0.f;
    }
}

// ---------------------------------------------------------------------------
// CSR build (once): group level-f edges by src; store LOCAL dst index.
// counts doubles as per-node in-degree.
// ---------------------------------------------------------------------------
__global__ void csr_count(const int* __restrict__ src, int* __restrict__ counts)
{
    int e = blockIdx.x * blockDim.x + threadIdx.x;
    if (e >= NE) return;
    int f = e / EPL;
    int sl = src[e] - f * NPL;
    atomicAdd(&counts[f * NPL + sl], 1);
}

__global__ void csr_scan(const int* __restrict__ counts, int* __restrict__ offs)
{
    int f = blockIdx.x;
    int t = threadIdx.x;
    const int base = f * NPL;
    const int CH = 40;
    __shared__ int part[256];
    int s = 0;
    for (int k = 0; k < CH; ++k) {
        int idx = t * CH + k;
        if (idx < NPL) s += counts[base + idx];
    }
    part[t] = s;
    __syncthreads();
    if (t == 0) {
        int run = 0;
        for (int j = 0; j < 256; ++j) { int tmp = part[j]; part[j] = run; run += tmp; }
    }
    __syncthreads();
    int run = part[t];
    for (int k = 0; k < CH; ++k) {
        int idx = t * CH + k;
        if (idx < NPL) { offs[base + idx] = run; run += counts[base + idx]; }
    }
}

__global__ void csr_fill(const int* __restrict__ src, const int* __restrict__ dst,
                         const int* __restrict__ offs, int* __restrict__ cursor,
                         int* __restrict__ nbrb)
{
    int e = blockIdx.x * blockDim.x + threadIdx.x;
    if (e >= NE) return;
    int f = e / EPL;
    int sl = src[e] - f * NPL;
    int p = atomicAdd(&cursor[f * NPL + sl], 1);
    nbrb[f * EPL + offs[f * NPL + sl] + p] = dst[e] - (f + 1) * NPL;
}

// pre0 = relu(b1) broadcast (+zero pads); pre1 pads zeroed
__global__ void pre_init(const float* __restrict__ b1,
                         float* __restrict__ pre0, float* __restrict__ pre1)
{
    int t = blockIdx.x * blockDim.x + threadIdx.x;
    if (t >= NPL * AP) return;
    int c = t % AP;
    pre0[t] = (c < H2) ? fmaxf(b1[c], 0.f) : 0.f;
    if (c >= H2) pre1[t] = 0.f;
}

// ---------------------------------------------------------------------------
// Fused level step v5. 512 threads, TN=20 nodes/block, 500 blocks.
// LDS ~76 KB -> 2 blocks/CU (launch_bounds(512,4)): phases of co-resident
// blocks overlap (A gather latency / B,C VALU / D LDS).
//  stage: LDS weights, edge meta, xr
//  A: gather pre50 rows -> smA (aliased into Y storage)
//  B: p50 = relu(agg@WaT + deg*b2p + pb1) -> smP   (Wc VGPR loads issue here)
//  C: Y[n][c] = b4i[c] + smP[n]·Wc + xs[n]·wx   (12x float4 + 2-scalar tail;
//     Wc is exactly 50 entries — NO OOB, no dependence on smP pads)
//  GRU: flat (n,o) loop: r=sig(Y1) z=sig(Y2) t=tanh(inn+r*Y3) h=(1-z)t+z*Y0
//       -> hs (for D) AND state_out (coalesced)
//  D: pre50_out = relu(nb1 + hs@nwT)
// ---------------------------------------------------------------------------
__global__ __launch_bounds__(512, 4) void k3_kernel(
    const float* __restrict__ preIn, float* __restrict__ preOut,
    const int* __restrict__ fedge, int srcbase,
    const int* __restrict__ boffs, const int* __restrict__ bdeg,
    const int* __restrict__ bnbr,
    const float* __restrict__ xrL,
    const float* __restrict__ WaT, const float* __restrict__ b2p,
    const float* __restrict__ pb1,
    const float* __restrict__ W4i, const float* __restrict__ b4i,
    const float* __restrict__ wi, const float* __restrict__ bi,
    const float* __restrict__ nwT, const float* __restrict__ nb1,
    float* __restrict__ state_out)
{
    __shared__ __attribute__((aligned(16))) float Y[TN * YS];      // 32.0 KB (smA aliased inside)
    __shared__ __attribute__((aligned(16))) float smP[TN * AP];    //  4.2 KB
    __shared__ __attribute__((aligned(16))) float sWaT[H2 * AP];   // 10.4 KB
    __shared__ __attribute__((aligned(16))) float sNwT[H2 * NWS];  // 21.6 KB
    __shared__ __attribute__((aligned(16))) float hs[TN * HSS];    //  8.0 KB
    __shared__ __attribute__((aligned(16))) float xs[TN * FD];
    __shared__ int sed[TN * KE];
    __shared__ int soff[TN];
    __shared__ int sdeg[TN];

    float* const smA = Y;              // smA dead before Y is written (phase C)

    int tid = threadIdx.x;
    int nb = blockIdx.x * TN;
    int c = tid;                       // output col for phase C
    int g = c & 3, o4 = c >> 2;

    // ---- stage: LDS weights, xs, edge metadata ----
    for (int idx = tid; idx < H2 * AP / 4; idx += 512)
        ((float4*)sWaT)[idx] = ((const float4*)WaT)[idx];
    for (int idx = tid; idx < H2 * NWS / 4; idx += 512)
        ((float4*)sNwT)[idx] = ((const float4*)nwT)[idx];
    if (tid < TN)
        ((float4*)xs)[tid] = ((const float4*)xrL)[nb + tid];
    if (fedge) {
        if (tid < TN * KE) sed[tid] = fedge[nb * KE + tid] - srcbase;
    } else {
        if (tid < TN) { soff[tid] = boffs[nb + tid]; sdeg[tid] = bdeg[nb + tid]; }
    }
    __syncthreads();

    // ---- phase A: gather + sum pre50 rows -> smA ----
    const float4* pre4 = (const float4*)preIn;
    for (int idx = tid; idx < TN * 13; idx += 512) {
        int n = idx / 13, q = idx - n * 13;
        float4 a = make_float4(0.f, 0.f, 0.f, 0.f);
        if (fedge) {
#pragma unroll
            for (int e = 0; e < KE; ++e) {
                int r = sed[KE * n + e];
                float4 v = pre4[r * 13 + q];
                a.x += v.x; a.y += v.y; a.z += v.z; a.w += v.w;
            }
        } else {
            int off = soff[n], d = sdeg[n];
            for (int e = 0; e < d; ++e) {
                int r = bnbr[off + e];
                float4 v = pre4[r * 13 + q];
                a.x += v.x; a.y += v.y; a.z += v.z; a.w += v.w;
            }
        }
        *(float4*)&smA[n * AP + 4 * q] = a;
    }
    __syncthreads();

    // ---- per-thread C weights: issue here, latency hidden under phase B ----
    float Wc[H2];
    float b4c = 0.f, wx0 = 0.f, wx1 = 0.f, wx2 = 0.f, wx3 = 0.f;
    if (c < 400) {
#pragma unroll
        for (int k = 0; k < H2; ++k) Wc[k] = W4i[k * 400 + c];
        b4c = b4i[c];
        if (g == 1 || g == 2) {
            int off = ((g == 1) ? o4 : (100 + o4)) * 4;
            wx0 = wi[off + 0]; wx1 = wi[off + 1]; wx2 = wi[off + 2]; wx3 = wi[off + 3];
        }
    }

    // ---- phase B: p50 -> smP ----
    for (int idx = tid; idx < TN * H2; idx += 512) {
        int n = idx / H2, cc = idx - n * H2;
        float dgv = fedge ? 3.0f : (float)sdeg[n];
        float acc = pb1[cc] + dgv * b2p[cc];
        const float4* ar = (const float4*)&smA[n * AP];
        const float4* wr = (const float4*)&sWaT[cc * AP];
#pragma unroll
        for (int q = 0; q < 13; ++q) {
            float4 av = ar[q], wv = wr[q];
            acc = fmaf(av.x, wv.x, acc); acc = fmaf(av.y, wv.y, acc);
            acc = fmaf(av.z, wv.z, acc); acc = fmaf(av.w, wv.w, acc);
        }
        smP[n * AP + cc] = fmaxf(acc, 0.f);
    }
    __syncthreads();

    // ---- phase C: Y = b4 + P@W4i + xs@wx (48 via float4, tail 48..49 scalar) ----
    if (c < 400) {
#pragma unroll 2
        for (int n = 0; n < TN; ++n) {
            const float* prf = &smP[n * AP];
            const float4* pr = (const float4*)prf;
            float acc = b4c;
#pragma unroll
            for (int q = 0; q < 12; ++q) {
                float4 pv = pr[q];
                acc = fmaf(pv.x, Wc[4 * q + 0], acc);
                acc = fmaf(pv.y, Wc[4 * q + 1], acc);
                acc = fmaf(pv.z, Wc[4 * q + 2], acc);
                acc = fmaf(pv.w, Wc[4 * q + 3], acc);
            }
            acc = fmaf(prf[48], Wc[48], acc);
            acc = fmaf(prf[49], Wc[49], acc);
            float4 xv = *(const float4*)&xs[n * FD];
            acc = fmaf(xv.x, wx0, acc); acc = fmaf(xv.y, wx1, acc);
            acc = fmaf(xv.z, wx2, acc); acc = fmaf(xv.w, wx3, acc);
            Y[n * YS + c] = acc;
        }
    }
    __syncthreads();

    // ---- GRU: flat (n,o) pairs across all 512 threads; fused state write ----
    for (int p = tid; p < TN * H; p += 512) {
        int n = p / H, o = p - n * H;
        float4 yv = *(const float4*)&Y[n * YS + 4 * o];
        float4 xv = *(const float4*)&xs[n * FD];
        float inn = bi[200 + o] + xv.x * wi[(200 + o) * 4 + 0]
                                + xv.y * wi[(200 + o) * 4 + 1]
                                + xv.z * wi[(200 + o) * 4 + 2]
                                + xv.w * wi[(200 + o) * 4 + 3];
        float r = sigmoidf_(yv.y);
        float z = sigmoidf_(yv.z);
        float t = tanhf_(inn + r * yv.w);
        float h = fmaf(z, yv.x - t, t);   // (1-z)t + z*m
        hs[n * HSS + o] = h;
        state_out[(size_t)(nb + n) * H + o] = h;
    }
    __syncthreads();

    // ---- phase D: next step's pre50 ----
    for (int idx = tid; idx < TN * H2; idx += 512) {
        int n = idx / H2, cc = idx - n * H2;
        float acc = nb1[cc];
        const float4* hr = (const float4*)&hs[n * HSS];
        const float4* wr = (const float4*)&sNwT[cc * NWS];
#pragma unroll
        for (int q = 0; q < 25; ++q) {
            float4 hv = hr[q], wv = wr[q];
            acc = fmaf(hv.x, wv.x, acc); acc = fmaf(hv.y, wv.y, acc);
            acc = fmaf(hv.z, wv.z, acc); acc = fmaf(hv.w, wv.w, acc);
        }
        preOut[(size_t)(nb + n) * AP + cc] = fmaxf(acc, 0.f);
    }
}

// ---------------------------------------------------------------------------
// xr = state @ proj_w + proj_b ; thread = (node, f)
// ---------------------------------------------------------------------------
__global__ __launch_bounds__(256) void proj_kernel(
    const float* __restrict__ state, const float* __restrict__ pw,
    const float* __restrict__ pb, float* __restrict__ xr)
{
    int t = blockIdx.x * 256 + threadIdx.x;
    if (t >= NT * FD) return;
    int node = t >> 2, f = t & 3;
    const float4* rp = (const float4*)(state + (size_t)node * H);
    float acc = pb[f];
    for (int i4 = 0; i4 < 25; ++i4) {
        float4 v = rp[i4];
        acc = fmaf(v.x, pw[(4 * i4 + 0) * 4 + f], acc);
        acc = fmaf(v.y, pw[(4 * i4 + 1) * 4 + f], acc);
        acc = fmaf(v.z, pw[(4 * i4 + 2) * 4 + f], acc);
        acc = fmaf(v.w, pw[(4 * i4 + 3) * 4 + f], acc);
    }
    xr[t] = acc;
}

// ---------------------------------------------------------------------------
__global__ void cls_kernel(const float* __restrict__ state,
                           const float* __restrict__ w1, const float* __restrict__ b1,
                           const float* __restrict__ w2, const float* __restrict__ b2,
                           float* __restrict__ pred)
{
    int n = blockIdx.x * blockDim.x + threadIdx.x;
    if (n >= NPL) return;
    float h[DM];
#pragma unroll
    for (int j = 0; j < DM; ++j) h[j] = b1[j];
    const float* sp = state + (size_t)n * H;
    for (int i = 0; i < H; ++i) {
        float s = sp[i];
#pragma unroll
        for (int j = 0; j < DM; ++j) h[j] = fmaf(s, w1[i * DM + j], h[j]);
    }
    float v = b2[0];
#pragma unroll
    for (int j = 0; j < DM; ++j) v = fmaf(fmaxf(h[j], 0.f), w2[j], v);
    pred[n] = sigmoidf_(v);
}

// ---------------------------------------------------------------------------
__global__ void gate_kernel(const float* __restrict__ x, const int* __restrict__ src,
                            float* __restrict__ pred, int l)
{
    int j = blockIdx.x * blockDim.x + threadIdx.x;
    if (j >= NPL) return;
    int e0 = (l - 1) * EPL + KE * j;
    int dg = l * NPL + j;
    float v0 = pred[src[e0 + 0]];
    float v1 = pred[src[e0 + 1]];
    float v2 = pred[src[e0 + 2]];
    const float invT = 100.0f;
    float mx = fmaxf(v0, fmaxf(v1, v2));
    float e0x = __expf((v0 - mx) * invT);
    float e1x = __expf((v1 - mx) * invT);
    float e2x = __expf((v2 - mx) * invT);
    float smax = (e0x * v0 + e1x * v1 + e2x * v2) / (e0x + e1x + e2x);
    float mn = fminf(v0, fminf(v1, v2));
    float f0 = __expf((mn - v0) * invT);
    float f1 = __expf((mn - v1) * invT);
    float f2 = __expf((mn - v2) * invT);
    float smin = (f0 * v0 + f1 * v1 + f2 * v2) / (f0 + f1 + f2);
    float am = x[(size_t)dg * FD + 1];
    float om = x[(size_t)dg * FD + 2];
    float nm = x[(size_t)dg * FD + 3];
    pred[dg] = am * smin + om * smax + nm * (3.f - (v0 + v1 + v2));
}

__global__ void copy_kernel(const float* __restrict__ pred, float* __restrict__ out)
{
    int j = blockIdx.x * blockDim.x + threadIdx.x;
    if (j < NPL) out[j] = pred[(NLV - 1) * NPL + j];
}

// ---------------------------------------------------------------------------
extern "C" void kernel_launch(void* const* d_in, const int* in_sizes, int n_in,
                              void* d_out, int out_size, void* d_ws, size_t ws_size,
                              hipStream_t stream)
{
    const float* x        = (const float*)d_in[0];
    const float* fpre_w1  = (const float*)d_in[1];
    const float* fpre_b1  = (const float*)d_in[2];
    const float* fpre_w2  = (const float*)d_in[3];
    const float* fpre_b2  = (const float*)d_in[4];
    const float* fpost_w1 = (const float*)d_in[5];
    const float* fpost_b1 = (const float*)d_in[6];
    const float* fpost_w2 = (const float*)d_in[7];
    const float* fpost_b2 = (const float*)d_in[8];
    const float* bpre_w1  = (const float*)d_in[9];
    const float* bpre_b1  = (const float*)d_in[10];
    const float* bpre_w2  = (const float*)d_in[11];
    const float* bpre_b2  = (const float*)d_in[12];
    const float* bpost_w1 = (const float*)d_in[13];
    const float* bpost_b1 = (const float*)d_in[14];
    const float* bpost_w2 = (const float*)d_in[15];
    const float* bpost_b2 = (const float*)d_in[16];
    const float* gruf_wi  = (const float*)d_in[17];
    const float* gruf_wh  = (const float*)d_in[18];
    const float* gruf_bi  = (const float*)d_in[19];
    const float* gruf_bh  = (const float*)d_in[20];
    const float* grub_wi  = (const float*)d_in[21];
    const float* grub_wh  = (const float*)d_in[22];
    const float* grub_bi  = (const float*)d_in[23];
    const float* grub_bh  = (const float*)d_in[24];
    const float* proj_w   = (const float*)d_in[25];
    const float* proj_b   = (const float*)d_in[26];
    const float* cls_w1   = (const float*)d_in[27];
    const float* cls_b1   = (const float*)d_in[28];
    const float* cls_w2   = (const float*)d_in[29];
    const float* cls_b2   = (const float*)d_in[30];
    const int*   src      = (const int*)d_in[31];
    const int*   dst      = (const int*)d_in[32];
    float* out = (float*)d_out;

    size_t o = 0;
    auto carve = [&](size_t nbytes) -> void* {
        void* p = (char*)d_ws + o;
        o += (nbytes + 255) & ~(size_t)255;
        return p;
    };
    float* state = (float*)carve((size_t)NT * H * 4);        // 48 MB
    float* xr    = (float*)carve((size_t)NT * FD * 4);
    float* pred  = (float*)carve((size_t)NT * 4);
    float* pre0  = (float*)carve((size_t)NPL * AP * 4);      // 2.08 MB
    float* pre1  = (float*)carve((size_t)NPL * AP * 4);
    int*   counts= (int*)carve((size_t)11 * NPL * 4);
    int*   cursor= (int*)carve((size_t)11 * NPL * 4);
    int*   offs  = (int*)carve((size_t)11 * NPL * 4);
    int*   nbrb  = (int*)carve((size_t)NE * 4);
    float* WaTF  = (float*)carve(H2 * AP * 4);
    float* b2pF  = (float*)carve(64 * 4);
    float* W4iF  = (float*)carve(H2 * 400 * 4);
    float* b4iF  = (float*)carve(400 * 4);
    float* nwTF  = (float*)carve(H2 * NWS * 4);
    float* WaTB  = (float*)carve(H2 * AP * 4);
    float* b2pB  = (float*)carve(64 * 4);
    float* W4iB  = (float*)carve(H2 * 400 * 4);
    float* b4iB  = (float*)carve(400 * 4);
    float* nwTB  = (float*)carve(H2 * NWS * 4);

    // zero counts AND cursor INCLUDING alignment padding between them
    hipMemsetAsync(counts, 0, (size_t)((char*)offs - (char*)counts), stream);

    fold_kernel<<<(2 * 28350 + 255) / 256, 256, 0, stream>>>(
        fpre_w2, fpre_b2, fpost_w1, fpost_w2, fpost_b2, gruf_wh, gruf_bh, gruf_bi, fpre_w1,
        bpre_w2, bpre_b2, bpost_w1, bpost_w2, bpost_b2, grub_wh, grub_bh, grub_bi, bpre_w1,
        WaTF, b2pF, W4iF, b4iF, nwTF,
        WaTB, b2pB, W4iB, b4iB, nwTB);
    csr_count<<<(NE + 255) / 256, 256, 0, stream>>>(src, counts);
    csr_scan<<<11, 256, 0, stream>>>(counts, offs);
    csr_fill<<<(NE + 255) / 256, 256, 0, stream>>>(src, dst, offs, cursor, nbrb);
    pre_init<<<(NPL * AP + 255) / 256, 256, 0, stream>>>(fpre_b1, pre0, pre1);

    float* preBuf[2] = { pre0, pre1 };
    int pb = 0;
    const int k3Grid = NPL / TN;   // 500

    for (int r = 0; r < 2; ++r) {
        const float* xr_use;
        if (r == 0) {
            xr_use = x;
        } else {
            proj_kernel<<<(NT * FD + 255) / 256, 256, 0, stream>>>(state, proj_w, proj_b, xr);
            xr_use = xr;
        }
        // forward levels 1..11
        for (int l = 1; l < NLV; ++l) {
            bool lastf = (l == NLV - 1);
            k3_kernel<<<k3Grid, 512, 0, stream>>>(
                preBuf[pb], preBuf[pb ^ 1],
                src + (size_t)(l - 1) * EPL, (l - 1) * NPL,
                nullptr, nullptr, nullptr,
                xr_use + (size_t)l * NPL * FD,
                WaTF, b2pF, fpost_b1, W4iF, b4iF, gruf_wi, gruf_bi,
                lastf ? nwTB : nwTF, lastf ? bpre_b1 : fpre_b1,
                state + (size_t)l * NPL * H);
            pb ^= 1;
        }
        // backward levels 10..0
        for (int f = NLV - 2; f >= 0; --f) {
            bool lastb = (f == 0);
            k3_kernel<<<k3Grid, 512, 0, stream>>>(
                preBuf[pb], preBuf[pb ^ 1],
                nullptr, 0,
                offs + (size_t)f * NPL, counts + (size_t)f * NPL, nbrb + (size_t)f * EPL,
                xr_use + (size_t)f * NPL * FD,
                WaTB, b2pB, bpost_b1, W4iB, b4iB, grub_wi, grub_bi,
                lastb ? nwTF : nwTB, lastb ? fpre_b1 : bpre_b1,
                state + (size_t)f * NPL * H);
            pb ^= 1;
        }
    }

    cls_kernel<<<(NPL + 255) / 256, 256, 0, stream>>>(state, cls_w1, cls_b1, cls_w2, cls_b2, pred);
    for (int l = 1; l < NLV; ++l)
        gate_kernel<<<(NPL + 255) / 256, 256, 0, stream>>>(x, src, pred, l);
    copy_kernel<<<(NPL + 255) / 256, 256, 0, stream>>>(pred, out);
}

// Round 4
// 1245.468 us; speedup vs baseline: 2.5904x; 2.5904x over previous
//
#include <hip/hip_runtime.h>
#include <cstdint>
#include <cstddef>

#define NLV 12
#define NPL 10000
#define KE 3
#define EPL (NPL * KE)   // 30000 edges per level block
#define NE (11 * EPL)    // 330000
#define NT (NLV * NPL)   // 120000 nodes
#define H 100
#define H2 50
#define FD 4
#define DM 30
#define AP 52            // pre50 row stride (13 float4)
#define TN 20            // nodes per block (500 blocks exactly)
#define YS 400           // Y LDS row stride (dwords)
#define HSS 100          // hs LDS row stride
#define NWS 108          // nwT row stride

__device__ __forceinline__ float sigmoidf_(float x) {
    return 1.0f / (1.0f + __expf(-x));
}
__device__ __forceinline__ float tanhf_(float x) {
    float e = __expf(2.0f * x);
    return 1.0f - 2.0f / (e + 1.0f);
}

// ---------------------------------------------------------------------------
// Weight folding per direction (PER = 28350 outputs):
//  WaT[c*52+k]   = (w2@pw1)[k][c]                        (i < 2500)
//  b2p[c]        = (b2@pw1)[c]                           (2500..2550)
//  W4i[k*400+c]  c=4o+g: g0: pw2[k][o]                   (2550..22550)
//                g1..3: sum_m pw2[k][m]*wh[(g-1)*100+o][m]
//  b4i[c]        g0: pb2[o]; g1: bh[o]+fold+bi[o];       (22550..22950)
//                g2: bh[100+o]+fold+bi[100+o]; g3: bh[200+o]+fold
//  nwT[c*108+k]  = (k<100) ? w1pre[k*50+c] : 0           (22950..28350)
// ---------------------------------------------------------------------------
__global__ void fold_kernel(
    const float* __restrict__ w2F, const float* __restrict__ b2F_,
    const float* __restrict__ pw1F, const float* __restrict__ pw2F,
    const float* __restrict__ pb2F, const float* __restrict__ whF,
    const float* __restrict__ bhF, const float* __restrict__ biF,
    const float* __restrict__ w1pF,
    const float* __restrict__ w2B, const float* __restrict__ b2B_,
    const float* __restrict__ pw1B, const float* __restrict__ pw2B,
    const float* __restrict__ pb2B, const float* __restrict__ whB,
    const float* __restrict__ bhB, const float* __restrict__ biB,
    const float* __restrict__ w1pB,
    float* __restrict__ WaTF, float* __restrict__ b2pF,
    float* __restrict__ W4iF, float* __restrict__ b4iF, float* __restrict__ nwTF,
    float* __restrict__ WaTB, float* __restrict__ b2pB,
    float* __restrict__ W4iB, float* __restrict__ b4iB, float* __restrict__ nwTB)
{
    const int PER = 28350;
    int gid = blockIdx.x * blockDim.x + threadIdx.x;
    if (gid >= 2 * PER) return;
    int dir = gid / PER;
    int i = gid - dir * PER;
    const float* w2  = dir ? w2B  : w2F;
    const float* b2  = dir ? b2B_ : b2F_;
    const float* pw1 = dir ? pw1B : pw1F;
    const float* pw2 = dir ? pw2B : pw2F;
    const float* pb2 = dir ? pb2B : pb2F;
    const float* wh  = dir ? whB  : whF;
    const float* bh  = dir ? bhB  : bhF;
    const float* bi  = dir ? biB  : biF;
    const float* w1p = dir ? w1pB : w1pF;
    float* WaT = dir ? WaTB : WaTF;
    float* b2p = dir ? b2pB : b2pF;
    float* W4i = dir ? W4iB : W4iF;
    float* b4i = dir ? b4iB : b4iF;
    float* nwT = dir ? nwTB : nwTF;

    if (i < 2500) {
        int c = i / 50, k = i - c * 50;
        float s = 0.f;
        for (int m = 0; m < 100; ++m) s += w2[k * 100 + m] * pw1[m * 50 + c];
        WaT[c * AP + k] = s;
    } else if (i < 2550) {
        int c = i - 2500;
        float s = 0.f;
        for (int m = 0; m < 100; ++m) s += b2[m] * pw1[m * 50 + c];
        b2p[c] = s;
        // zero WaT row pads (row c, cols 50..51) so phase B never sees poison
        WaT[c * AP + 50] = 0.f;
        WaT[c * AP + 51] = 0.f;
    } else if (i < 22550) {
        int j = i - 2550;
        int k = j / 400, c = j - k * 400;
        int o = c >> 2, g = c & 3;
        float s;
        if (g == 0) {
            s = pw2[k * 100 + o];
        } else {
            int row = (g - 1) * 100 + o;
            s = 0.f;
            for (int m = 0; m < 100; ++m) s += pw2[k * 100 + m] * wh[row * 100 + m];
        }
        W4i[k * 400 + c] = s;
    } else if (i < 22950) {
        int c = i - 22550;
        int o = c >> 2, g = c & 3;
        float s;
        if (g == 0) {
            s = pb2[o];
        } else {
            int row = (g - 1) * 100 + o;
            s = bh[row];
            for (int m = 0; m < 100; ++m) s += pb2[m] * wh[row * 100 + m];
            if (g == 1) s += bi[o];
            else if (g == 2) s += bi[100 + o];
        }
        b4i[c] = s;
    } else {
        int j = i - 22950;
        int c = j / NWS, k = j - c * NWS;
        nwT[c * NWS + k] = (k < 100) ? w1p[k * 50 + c] : 0.f;
    }
}

// ---------------------------------------------------------------------------
// CSR build (once): group level-f edges by src; store LOCAL dst index.
// counts doubles as per-node in-degree.
// ---------------------------------------------------------------------------
__global__ void csr_count(const int* __restrict__ src, int* __restrict__ counts)
{
    int e = blockIdx.x * blockDim.x + threadIdx.x;
    if (e >= NE) return;
    int f = e / EPL;
    int sl = src[e] - f * NPL;
    atomicAdd(&counts[f * NPL + sl], 1);
}

__global__ void csr_scan(const int* __restrict__ counts, int* __restrict__ offs)
{
    int f = blockIdx.x;
    int t = threadIdx.x;
    const int base = f * NPL;
    const int CH = 40;
    __shared__ int part[256];
    int s = 0;
    for (int k = 0; k < CH; ++k) {
        int idx = t * CH + k;
        if (idx < NPL) s += counts[base + idx];
    }
    part[t] = s;
    __syncthreads();
    if (t == 0) {
        int run = 0;
        for (int j = 0; j < 256; ++j) { int tmp = part[j]; part[j] = run; run += tmp; }
    }
    __syncthreads();
    int run = part[t];
    for (int k = 0; k < CH; ++k) {
        int idx = t * CH + k;
        if (idx < NPL) { offs[base + idx] = run; run += counts[base + idx]; }
    }
}

__global__ void csr_fill(const int* __restrict__ src, const int* __restrict__ dst,
                         const int* __restrict__ offs, int* __restrict__ cursor,
                         int* __restrict__ nbrb)
{
    int e = blockIdx.x * blockDim.x + threadIdx.x;
    if (e >= NE) return;
    int f = e / EPL;
    int sl = src[e] - f * NPL;
    int p = atomicAdd(&cursor[f * NPL + sl], 1);
    nbrb[f * EPL + offs[f * NPL + sl] + p] = dst[e] - (f + 1) * NPL;
}

// pre0 = relu(b1) broadcast (+zero pads); pre1 pads zeroed
__global__ void pre_init(const float* __restrict__ b1,
                         float* __restrict__ pre0, float* __restrict__ pre1)
{
    int t = blockIdx.x * blockDim.x + threadIdx.x;
    if (t >= NPL * AP) return;
    int c = t % AP;
    pre0[t] = (c < H2) ? fmaxf(b1[c], 0.f) : 0.f;
    if (c >= H2) pre1[t] = 0.f;
}

// ---------------------------------------------------------------------------
// Fused level step v6. 512 threads, TN=20 nodes/block, 500 blocks.
// LDS ~76 KB -> 2 blocks/CU (launch_bounds(512,4) caps VGPR at 128).
// Phase C is K-split so peak register pressure ~75 (acc[20] + Wq[24] + 6
// float4 in flight) — the v5 spill (Wc[50] + unroll2*13 float4 > 128) is
// structurally impossible here.
//  stage: LDS weights, edge meta, xr
//  A: gather pre50 rows -> smA (aliased into Y storage)
//  B: p50 = relu(agg@WaT + deg*b2p + pb1) -> smP
//  C: acc[n] = b4i[c] + xs[n]@wx; two passes k=[0,24),[24,48) streaming
//     Wq[24] from W4i + tail k=48,49; write Y[n][c]
//  GRU: flat (n,o) loop -> hs AND state_out (coalesced)
//  D: pre50_out = relu(nb1 + hs@nwT)
// ---------------------------------------------------------------------------
__global__ __launch_bounds__(512, 4) void k3_kernel(
    const float* __restrict__ preIn, float* __restrict__ preOut,
    const int* __restrict__ fedge, int srcbase,
    const int* __restrict__ boffs, const int* __restrict__ bdeg,
    const int* __restrict__ bnbr,
    const float* __restrict__ xrL,
    const float* __restrict__ WaT, const float* __restrict__ b2p,
    const float* __restrict__ pb1,
    const float* __restrict__ W4i, const float* __restrict__ b4i,
    const float* __restrict__ wi, const float* __restrict__ bi,
    const float* __restrict__ nwT, const float* __restrict__ nb1,
    float* __restrict__ state_out)
{
    __shared__ __attribute__((aligned(16))) float Y[TN * YS];      // 32.0 KB (smA aliased inside)
    __shared__ __attribute__((aligned(16))) float smP[TN * AP];    //  4.2 KB
    __shared__ __attribute__((aligned(16))) float sWaT[H2 * AP];   // 10.4 KB
    __shared__ __attribute__((aligned(16))) float sNwT[H2 * NWS];  // 21.6 KB
    __shared__ __attribute__((aligned(16))) float hs[TN * HSS];    //  8.0 KB
    __shared__ __attribute__((aligned(16))) float xs[TN * FD];
    __shared__ int sed[TN * KE];
    __shared__ int soff[TN];
    __shared__ int sdeg[TN];

    float* const smA = Y;              // smA dead before Y is written (phase C)

    int tid = threadIdx.x;
    int nb = blockIdx.x * TN;
    int c = tid;                       // output col for phase C
    int g = c & 3, o4 = c >> 2;

    // ---- stage: LDS weights, xs, edge metadata ----
    for (int idx = tid; idx < H2 * AP / 4; idx += 512)
        ((float4*)sWaT)[idx] = ((const float4*)WaT)[idx];
    for (int idx = tid; idx < H2 * NWS / 4; idx += 512)
        ((float4*)sNwT)[idx] = ((const float4*)nwT)[idx];
    if (tid < TN)
        ((float4*)xs)[tid] = ((const float4*)xrL)[nb + tid];
    if (fedge) {
        if (tid < TN * KE) sed[tid] = fedge[nb * KE + tid] - srcbase;
    } else {
        if (tid < TN) { soff[tid] = boffs[nb + tid]; sdeg[tid] = bdeg[nb + tid]; }
    }
    __syncthreads();

    // ---- phase A: gather + sum pre50 rows -> smA ----
    const float4* pre4 = (const float4*)preIn;
    for (int idx = tid; idx < TN * 13; idx += 512) {
        int n = idx / 13, q = idx - n * 13;
        float4 a = make_float4(0.f, 0.f, 0.f, 0.f);
        if (fedge) {
#pragma unroll
            for (int e = 0; e < KE; ++e) {
                int r = sed[KE * n + e];
                float4 v = pre4[r * 13 + q];
                a.x += v.x; a.y += v.y; a.z += v.z; a.w += v.w;
            }
        } else {
            int off = soff[n], d = sdeg[n];
            for (int e = 0; e < d; ++e) {
                int r = bnbr[off + e];
                float4 v = pre4[r * 13 + q];
                a.x += v.x; a.y += v.y; a.z += v.z; a.w += v.w;
            }
        }
        *(float4*)&smA[n * AP + 4 * q] = a;
    }
    __syncthreads();

    // ---- per-thread C bias/input weights (5 regs live across B) ----
    float b4c = 0.f, wx0 = 0.f, wx1 = 0.f, wx2 = 0.f, wx3 = 0.f;
    if (c < 400) {
        b4c = b4i[c];
        if (g == 1 || g == 2) {
            int off = ((g == 1) ? o4 : (100 + o4)) * 4;
            wx0 = wi[off + 0]; wx1 = wi[off + 1]; wx2 = wi[off + 2]; wx3 = wi[off + 3];
        }
    }

    // ---- phase B: p50 -> smP ----
    for (int idx = tid; idx < TN * H2; idx += 512) {
        int n = idx / H2, cc = idx - n * H2;
        float dgv = fedge ? 3.0f : (float)sdeg[n];
        float acc = pb1[cc] + dgv * b2p[cc];
        const float4* ar = (const float4*)&smA[n * AP];
        const float4* wr = (const float4*)&sWaT[cc * AP];
#pragma unroll
        for (int q = 0; q < 13; ++q) {
            float4 av = ar[q], wv = wr[q];
            acc = fmaf(av.x, wv.x, acc); acc = fmaf(av.y, wv.y, acc);
            acc = fmaf(av.z, wv.z, acc); acc = fmaf(av.w, wv.w, acc);
        }
        smP[n * AP + cc] = fmaxf(acc, 0.f);
    }
    __syncthreads();

    // ---- phase C: Y = b4 + P@W4i + xs@wx  (K-split: 24 + 24 + 2 tail) ----
    if (c < 400) {
        float acc[TN];
#pragma unroll
        for (int n = 0; n < TN; ++n) {
            float4 xv = *(const float4*)&xs[n * FD];
            float a = b4c;
            a = fmaf(xv.x, wx0, a); a = fmaf(xv.y, wx1, a);
            a = fmaf(xv.z, wx2, a); a = fmaf(xv.w, wx3, a);
            acc[n] = a;
        }
        float Wq[24];
#pragma unroll
        for (int k = 0; k < 24; ++k) Wq[k] = W4i[k * 400 + c];
#pragma unroll
        for (int n = 0; n < TN; ++n) {
            const float4* pr = (const float4*)&smP[n * AP];
            float a = acc[n];
#pragma unroll
            for (int q = 0; q < 6; ++q) {
                float4 pv = pr[q];
                a = fmaf(pv.x, Wq[4 * q + 0], a);
                a = fmaf(pv.y, Wq[4 * q + 1], a);
                a = fmaf(pv.z, Wq[4 * q + 2], a);
                a = fmaf(pv.w, Wq[4 * q + 3], a);
            }
            acc[n] = a;
        }
#pragma unroll
        for (int k = 0; k < 24; ++k) Wq[k] = W4i[(24 + k) * 400 + c];
        float Wt0 = W4i[48 * 400 + c];
        float Wt1 = W4i[49 * 400 + c];
#pragma unroll
        for (int n = 0; n < TN; ++n) {
            const float* prf = &smP[n * AP];
            const float4* pr = (const float4*)(prf + 24);
            float a = acc[n];
#pragma unroll
            for (int q = 0; q < 6; ++q) {
                float4 pv = pr[q];
                a = fmaf(pv.x, Wq[4 * q + 0], a);
                a = fmaf(pv.y, Wq[4 * q + 1], a);
                a = fmaf(pv.z, Wq[4 * q + 2], a);
                a = fmaf(pv.w, Wq[4 * q + 3], a);
            }
            a = fmaf(prf[48], Wt0, a);
            a = fmaf(prf[49], Wt1, a);
            Y[n * YS + c] = a;
        }
    }
    __syncthreads();

    // ---- GRU: flat (n,o) pairs across all 512 threads; fused state write ----
    for (int p = tid; p < TN * H; p += 512) {
        int n = p / H, o = p - n * H;
        float4 yv = *(const float4*)&Y[n * YS + 4 * o];
        float4 xv = *(const float4*)&xs[n * FD];
        float inn = bi[200 + o] + xv.x * wi[(200 + o) * 4 + 0]
                                + xv.y * wi[(200 + o) * 4 + 1]
                                + xv.z * wi[(200 + o) * 4 + 2]
                                + xv.w * wi[(200 + o) * 4 + 3];
        float r = sigmoidf_(yv.y);
        float z = sigmoidf_(yv.z);
        float t = tanhf_(inn + r * yv.w);
        float h = fmaf(z, yv.x - t, t);   // (1-z)t + z*m
        hs[n * HSS + o] = h;
        state_out[(size_t)(nb + n) * H + o] = h;
    }
    __syncthreads();

    // ---- phase D: next step's pre50 ----
    for (int idx = tid; idx < TN * H2; idx += 512) {
        int n = idx / H2, cc = idx - n * H2;
        float acc = nb1[cc];
        const float4* hr = (const float4*)&hs[n * HSS];
        const float4* wr = (const float4*)&sNwT[cc * NWS];
#pragma unroll
        for (int q = 0; q < 25; ++q) {
            float4 hv = hr[q], wv = wr[q];
            acc = fmaf(hv.x, wv.x, acc); acc = fmaf(hv.y, wv.y, acc);
            acc = fmaf(hv.z, wv.z, acc); acc = fmaf(hv.w, wv.w, acc);
        }
        preOut[(size_t)(nb + n) * AP + cc] = fmaxf(acc, 0.f);
    }
}

// ---------------------------------------------------------------------------
// xr = state @ proj_w + proj_b ; thread = (node, f)
// ---------------------------------------------------------------------------
__global__ __launch_bounds__(256) void proj_kernel(
    const float* __restrict__ state, const float* __restrict__ pw,
    const float* __restrict__ pb, float* __restrict__ xr)
{
    int t = blockIdx.x * 256 + threadIdx.x;
    if (t >= NT * FD) return;
    int node = t >> 2, f = t & 3;
    const float4* rp = (const float4*)(state + (size_t)node * H);
    float acc = pb[f];
    for (int i4 = 0; i4 < 25; ++i4) {
        float4 v = rp[i4];
        acc = fmaf(v.x, pw[(4 * i4 + 0) * 4 + f], acc);
        acc = fmaf(v.y, pw[(4 * i4 + 1) * 4 + f], acc);
        acc = fmaf(v.z, pw[(4 * i4 + 2) * 4 + f], acc);
        acc = fmaf(v.w, pw[(4 * i4 + 3) * 4 + f], acc);
    }
    xr[t] = acc;
}

// ---------------------------------------------------------------------------
__global__ void cls_kernel(const float* __restrict__ state,
                           const float* __restrict__ w1, const float* __restrict__ b1,
                           const float* __restrict__ w2, const float* __restrict__ b2,
                           float* __restrict__ pred)
{
    int n = blockIdx.x * blockDim.x + threadIdx.x;
    if (n >= NPL) return;
    float h[DM];
#pragma unroll
    for (int j = 0; j < DM; ++j) h[j] = b1[j];
    const float* sp = state + (size_t)n * H;
    for (int i = 0; i < H; ++i) {
        float s = sp[i];
#pragma unroll
        for (int j = 0; j < DM; ++j) h[j] = fmaf(s, w1[i * DM + j], h[j]);
    }
    float v = b2[0];
#pragma unroll
    for (int j = 0; j < DM; ++j) v = fmaf(fmaxf(h[j], 0.f), w2[j], v);
    pred[n] = sigmoidf_(v);
}

// ---------------------------------------------------------------------------
__global__ void gate_kernel(const float* __restrict__ x, const int* __restrict__ src,
                            float* __restrict__ pred, int l)
{
    int j = blockIdx.x * blockDim.x + threadIdx.x;
    if (j >= NPL) return;
    int e0 = (l - 1) * EPL + KE * j;
    int dg = l * NPL + j;
    float v0 = pred[src[e0 + 0]];
    float v1 = pred[src[e0 + 1]];
    float v2 = pred[src[e0 + 2]];
    const float invT = 100.0f;
    float mx = fmaxf(v0, fmaxf(v1, v2));
    float e0x = __expf((v0 - mx) * invT);
    float e1x = __expf((v1 - mx) * invT);
    float e2x = __expf((v2 - mx) * invT);
    float smax = (e0x * v0 + e1x * v1 + e2x * v2) / (e0x + e1x + e2x);
    float mn = fminf(v0, fminf(v1, v2));
    float f0 = __expf((mn - v0) * invT);
    float f1 = __expf((mn - v1) * invT);
    float f2 = __expf((mn - v2) * invT);
    float smin = (f0 * v0 + f1 * v1 + f2 * v2) / (f0 + f1 + f2);
    float am = x[(size_t)dg * FD + 1];
    float om = x[(size_t)dg * FD + 2];
    float nm = x[(size_t)dg * FD + 3];
    pred[dg] = am * smin + om * smax + nm * (3.f - (v0 + v1 + v2));
}

__global__ void copy_kernel(const float* __restrict__ pred, float* __restrict__ out)
{
    int j = blockIdx.x * blockDim.x + threadIdx.x;
    if (j < NPL) out[j] = pred[(NLV - 1) * NPL + j];
}

// ---------------------------------------------------------------------------
extern "C" void kernel_launch(void* const* d_in, const int* in_sizes, int n_in,
                              void* d_out, int out_size, void* d_ws, size_t ws_size,
                              hipStream_t stream)
{
    const float* x        = (const float*)d_in[0];
    const float* fpre_w1  = (const float*)d_in[1];
    const float* fpre_b1  = (const float*)d_in[2];
    const float* fpre_w2  = (const float*)d_in[3];
    const float* fpre_b2  = (const float*)d_in[4];
    const float* fpost_w1 = (const float*)d_in[5];
    const float* fpost_b1 = (const float*)d_in[6];
    const float* fpost_w2 = (const float*)d_in[7];
    const float* fpost_b2 = (const float*)d_in[8];
    const float* bpre_w1  = (const float*)d_in[9];
    const float* bpre_b1  = (const float*)d_in[10];
    const float* bpre_w2  = (const float*)d_in[11];
    const float* bpre_b2  = (const float*)d_in[12];
    const float* bpost_w1 = (const float*)d_in[13];
    const float* bpost_b1 = (const float*)d_in[14];
    const float* bpost_w2 = (const float*)d_in[15];
    const float* bpost_b2 = (const float*)d_in[16];
    const float* gruf_wi  = (const float*)d_in[17];
    const float* gruf_wh  = (const float*)d_in[18];
    const float* gruf_bi  = (const float*)d_in[19];
    const float* gruf_bh  = (const float*)d_in[20];
    const float* grub_wi  = (const float*)d_in[21];
    const float* grub_wh  = (const float*)d_in[22];
    const float* grub_bi  = (const float*)d_in[23];
    const float* grub_bh  = (const float*)d_in[24];
    const float* proj_w   = (const float*)d_in[25];
    const float* proj_b   = (const float*)d_in[26];
    const float* cls_w1   = (const float*)d_in[27];
    const float* cls_b1   = (const float*)d_in[28];
    const float* cls_w2   = (const float*)d_in[29];
    const float* cls_b2   = (const float*)d_in[30];
    const int*   src      = (const int*)d_in[31];
    const int*   dst      = (const int*)d_in[32];
    float* out = (float*)d_out;

    size_t o = 0;
    auto carve = [&](size_t nbytes) -> void* {
        void* p = (char*)d_ws + o;
        o += (nbytes + 255) & ~(size_t)255;
        return p;
    };
    float* state = (float*)carve((size_t)NT * H * 4);        // 48 MB
    float* xr    = (float*)carve((size_t)NT * FD * 4);
    float* pred  = (float*)carve((size_t)NT * 4);
    float* pre0  = (float*)carve((size_t)NPL * AP * 4);      // 2.08 MB
    float* pre1  = (float*)carve((size_t)NPL * AP * 4);
    int*   counts= (int*)carve((size_t)11 * NPL * 4);
    int*   cursor= (int*)carve((size_t)11 * NPL * 4);
    int*   offs  = (int*)carve((size_t)11 * NPL * 4);
    int*   nbrb  = (int*)carve((size_t)NE * 4);
    float* WaTF  = (float*)carve(H2 * AP * 4);
    float* b2pF  = (float*)carve(64 * 4);
    float* W4iF  = (float*)carve(H2 * 400 * 4);
    float* b4iF  = (float*)carve(400 * 4);
    float* nwTF  = (float*)carve(H2 * NWS * 4);
    float* WaTB  = (float*)carve(H2 * AP * 4);
    float* b2pB  = (float*)carve(64 * 4);
    float* W4iB  = (float*)carve(H2 * 400 * 4);
    float* b4iB  = (float*)carve(400 * 4);
    float* nwTB  = (float*)carve(H2 * NWS * 4);

    // zero counts AND cursor INCLUDING alignment padding between them
    hipMemsetAsync(counts, 0, (size_t)((char*)offs - (char*)counts), stream);

    fold_kernel<<<(2 * 28350 + 255) / 256, 256, 0, stream>>>(
        fpre_w2, fpre_b2, fpost_w1, fpost_w2, fpost_b2, gruf_wh, gruf_bh, gruf_bi, fpre_w1,
        bpre_w2, bpre_b2, bpost_w1, bpost_w2, bpost_b2, grub_wh, grub_bh, grub_bi, bpre_w1,
        WaTF, b2pF, W4iF, b4iF, nwTF,
        WaTB, b2pB, W4iB, b4iB, nwTB);
    csr_count<<<(NE + 255) / 256, 256, 0, stream>>>(src, counts);
    csr_scan<<<11, 256, 0, stream>>>(counts, offs);
    csr_fill<<<(NE + 255) / 256, 256, 0, stream>>>(src, dst, offs, cursor, nbrb);
    pre_init<<<(NPL * AP + 255) / 256, 256, 0, stream>>>(fpre_b1, pre0, pre1);

    float* preBuf[2] = { pre0, pre1 };
    int pb = 0;
    const int k3Grid = NPL / TN;   // 500

    for (int r = 0; r < 2; ++r) {
        const float* xr_use;
        if (r == 0) {
            xr_use = x;
        } else {
            proj_kernel<<<(NT * FD + 255) / 256, 256, 0, stream>>>(state, proj_w, proj_b, xr);
            xr_use = xr;
        }
        // forward levels 1..11
        for (int l = 1; l < NLV; ++l) {
            bool lastf = (l == NLV - 1);
            k3_kernel<<<k3Grid, 512, 0, stream>>>(
                preBuf[pb], preBuf[pb ^ 1],
                src + (size_t)(l - 1) * EPL, (l - 1) * NPL,
                nullptr, nullptr, nullptr,
                xr_use + (size_t)l * NPL * FD,
                WaTF, b2pF, fpost_b1, W4iF, b4iF, gruf_wi, gruf_bi,
                lastf ? nwTB : nwTF, lastf ? bpre_b1 : fpre_b1,
                state + (size_t)l * NPL * H);
            pb ^= 1;
        }
        // backward levels 10..0
        for (int f = NLV - 2; f >= 0; --f) {
            bool lastb = (f == 0);
            k3_kernel<<<k3Grid, 512, 0, stream>>>(
                preBuf[pb], preBuf[pb ^ 1],
                nullptr, 0,
                offs + (size_t)f * NPL, counts + (size_t)f * NPL, nbrb + (size_t)f * EPL,
                xr_use + (size_t)f * NPL * FD,
                WaTB, b2pB, bpost_b1, W4iB, b4iB, grub_wi, grub_bi,
                lastb ? nwTF : nwTB, lastb ? fpre_b1 : bpre_b1,
                state + (size_t)f * NPL * H);
            pb ^= 1;
        }
    }

    cls_kernel<<<(NPL + 255) / 256, 256, 0, stream>>>(state, cls_w1, cls_b1, cls_w2, cls_b2, pred);
    for (int l = 1; l < NLV; ++l)
        gate_kernel<<<(NPL + 255) / 256, 256, 0, stream>>>(x, src, pred, l);
    copy_kernel<<<(NPL + 255) / 256, 256, 0, stream>>>(pred, out);
}

// Round 5
// 1241.345 us; speedup vs baseline: 2.5990x; 1.0033x over previous
//
#include <hip/hip_runtime.h>
#include <cstdint>
#include <cstddef>

#define NLV 12
#define NPL 10000
#define KE 3
#define EPL (NPL * KE)   // 30000 edges per level block
#define NE (11 * EPL)    // 330000
#define NT (NLV * NPL)   // 120000 nodes
#define H 100
#define H2 50
#define FD 4
#define DM 30
#define AP 52            // pre50 row stride (13 float4)
#define TN 20            // nodes per block (500 blocks exactly)
#define YS 400           // Y LDS row stride (dwords)
#define HSS 100          // hs LDS row stride
#define NWS 108          // nwT row stride

__device__ __forceinline__ float sigmoidf_(float x) {
    return 1.0f / (1.0f + __expf(-x));
}
__device__ __forceinline__ float tanhf_(float x) {
    float e = __expf(2.0f * x);
    return 1.0f - 2.0f / (e + 1.0f);
}

// ---------------------------------------------------------------------------
// Weight folding per direction (PER = 28350 outputs):
//  WaT[c*52+k]   = (w2@pw1)[k][c]                        (i < 2500)
//  b2p[c]        = (b2@pw1)[c]                           (2500..2550)
//  W4i[k*400+c]  c=4o+g: g0: pw2[k][o]                   (2550..22550)
//                g1..3: sum_m pw2[k][m]*wh[(g-1)*100+o][m]
//  b4i[c]        g0: pb2[o]; g1: bh[o]+fold+bi[o];       (22550..22950)
//                g2: bh[100+o]+fold+bi[100+o]; g3: bh[200+o]+fold
//  nwT[c*108+k]  = (k<100) ? w1pre[k*50+c] : 0           (22950..28350)
// ---------------------------------------------------------------------------
__global__ void fold_kernel(
    const float* __restrict__ w2F, const float* __restrict__ b2F_,
    const float* __restrict__ pw1F, const float* __restrict__ pw2F,
    const float* __restrict__ pb2F, const float* __restrict__ whF,
    const float* __restrict__ bhF, const float* __restrict__ biF,
    const float* __restrict__ w1pF,
    const float* __restrict__ w2B, const float* __restrict__ b2B_,
    const float* __restrict__ pw1B, const float* __restrict__ pw2B,
    const float* __restrict__ pb2B, const float* __restrict__ whB,
    const float* __restrict__ bhB, const float* __restrict__ biB,
    const float* __restrict__ w1pB,
    float* __restrict__ WaTF, float* __restrict__ b2pF,
    float* __restrict__ W4iF, float* __restrict__ b4iF, float* __restrict__ nwTF,
    float* __restrict__ WaTB, float* __restrict__ b2pB,
    float* __restrict__ W4iB, float* __restrict__ b4iB, float* __restrict__ nwTB)
{
    const int PER = 28350;
    int gid = blockIdx.x * blockDim.x + threadIdx.x;
    if (gid >= 2 * PER) return;
    int dir = gid / PER;
    int i = gid - dir * PER;
    const float* w2  = dir ? w2B  : w2F;
    const float* b2  = dir ? b2B_ : b2F_;
    const float* pw1 = dir ? pw1B : pw1F;
    const float* pw2 = dir ? pw2B : pw2F;
    const float* pb2 = dir ? pb2B : pb2F;
    const float* wh  = dir ? whB  : whF;
    const float* bh  = dir ? bhB  : bhF;
    const float* bi  = dir ? biB  : biF;
    const float* w1p = dir ? w1pB : w1pF;
    float* WaT = dir ? WaTB : WaTF;
    float* b2p = dir ? b2pB : b2pF;
    float* W4i = dir ? W4iB : W4iF;
    float* b4i = dir ? b4iB : b4iF;
    float* nwT = dir ? nwTB : nwTF;

    if (i < 2500) {
        int c = i / 50, k = i - c * 50;
        float s = 0.f;
        for (int m = 0; m < 100; ++m) s += w2[k * 100 + m] * pw1[m * 50 + c];
        WaT[c * AP + k] = s;
    } else if (i < 2550) {
        int c = i - 2500;
        float s = 0.f;
        for (int m = 0; m < 100; ++m) s += b2[m] * pw1[m * 50 + c];
        b2p[c] = s;
        // zero WaT row pads (row c, cols 50..51) so phase B never sees poison
        WaT[c * AP + 50] = 0.f;
        WaT[c * AP + 51] = 0.f;
    } else if (i < 22550) {
        int j = i - 2550;
        int k = j / 400, c = j - k * 400;
        int o = c >> 2, g = c & 3;
        float s;
        if (g == 0) {
            s = pw2[k * 100 + o];
        } else {
            int row = (g - 1) * 100 + o;
            s = 0.f;
            for (int m = 0; m < 100; ++m) s += pw2[k * 100 + m] * wh[row * 100 + m];
        }
        W4i[k * 400 + c] = s;
    } else if (i < 22950) {
        int c = i - 22550;
        int o = c >> 2, g = c & 3;
        float s;
        if (g == 0) {
            s = pb2[o];
        } else {
            int row = (g - 1) * 100 + o;
            s = bh[row];
            for (int m = 0; m < 100; ++m) s += pb2[m] * wh[row * 100 + m];
            if (g == 1) s += bi[o];
            else if (g == 2) s += bi[100 + o];
        }
        b4i[c] = s;
    } else {
        int j = i - 22950;
        int c = j / NWS, k = j - c * NWS;
        nwT[c * NWS + k] = (k < 100) ? w1p[k * 50 + c] : 0.f;
    }
}

// ---------------------------------------------------------------------------
// CSR build (once): group level-f edges by src; store LOCAL dst index.
// counts doubles as per-node in-degree.
// ---------------------------------------------------------------------------
__global__ void csr_count(const int* __restrict__ src, int* __restrict__ counts)
{
    int e = blockIdx.x * blockDim.x + threadIdx.x;
    if (e >= NE) return;
    int f = e / EPL;
    int sl = src[e] - f * NPL;
    atomicAdd(&counts[f * NPL + sl], 1);
}

__global__ void csr_scan(const int* __restrict__ counts, int* __restrict__ offs)
{
    int f = blockIdx.x;
    int t = threadIdx.x;
    const int base = f * NPL;
    const int CH = 40;
    __shared__ int part[256];
    int s = 0;
    for (int k = 0; k < CH; ++k) {
        int idx = t * CH + k;
        if (idx < NPL) s += counts[base + idx];
    }
    part[t] = s;
    __syncthreads();
    if (t == 0) {
        int run = 0;
        for (int j = 0; j < 256; ++j) { int tmp = part[j]; part[j] = run; run += tmp; }
    }
    __syncthreads();
    int run = part[t];
    for (int k = 0; k < CH; ++k) {
        int idx = t * CH + k;
        if (idx < NPL) { offs[base + idx] = run; run += counts[base + idx]; }
    }
}

__global__ void csr_fill(const int* __restrict__ src, const int* __restrict__ dst,
                         const int* __restrict__ offs, int* __restrict__ cursor,
                         int* __restrict__ nbrb)
{
    int e = blockIdx.x * blockDim.x + threadIdx.x;
    if (e >= NE) return;
    int f = e / EPL;
    int sl = src[e] - f * NPL;
    int p = atomicAdd(&cursor[f * NPL + sl], 1);
    nbrb[f * EPL + offs[f * NPL + sl] + p] = dst[e] - (f + 1) * NPL;
}

// pre0 = relu(b1) broadcast (+zero pads); pre1 pads zeroed
__global__ void pre_init(const float* __restrict__ b1,
                         float* __restrict__ pre0, float* __restrict__ pre1)
{
    int t = blockIdx.x * blockDim.x + threadIdx.x;
    if (t >= NPL * AP) return;
    int c = t % AP;
    pre0[t] = (c < H2) ? fmaxf(b1[c], 0.f) : 0.f;
    if (c >= H2) pre1[t] = 0.f;
}

// ---------------------------------------------------------------------------
// Fused level step v7. 512 threads, TN=20 nodes/block, 500 blocks.
// LDS ~76 KB; __launch_bounds__(512, 2): under hipcc's (CUDA-semantics)
// "min blocks per CU" 2nd arg this is 2 blocks/CU -> 16 waves/CU ->
// 4 waves/SIMD -> 128-VGPR cap. (Round-3 evidence: (512,4) produced
// VGPR_Count=64 = 512/8 waves -> the arg is blocks/CU, not waves/EU.)
// K-split phase C needs ~75-90 regs -> fits 128 with headroom, no spill.
//  stage: LDS weights, edge meta, xr
//  A: gather pre50 rows -> smA (aliased into Y storage)
//  B: p50 = relu(agg@WaT + deg*b2p + pb1) -> smP
//  C: acc[n] = b4i[c] + xs[n]@wx; two passes k=[0,24),[24,48) streaming
//     Wq[24] from W4i + tail k=48,49; write Y[n][c]
//  GRU: flat (n,o) loop -> hs AND state_out (coalesced)
//  D: pre50_out = relu(nb1 + hs@nwT)
// ---------------------------------------------------------------------------
__global__ __launch_bounds__(512, 2) void k3_kernel(
    const float* __restrict__ preIn, float* __restrict__ preOut,
    const int* __restrict__ fedge, int srcbase,
    const int* __restrict__ boffs, const int* __restrict__ bdeg,
    const int* __restrict__ bnbr,
    const float* __restrict__ xrL,
    const float* __restrict__ WaT, const float* __restrict__ b2p,
    const float* __restrict__ pb1,
    const float* __restrict__ W4i, const float* __restrict__ b4i,
    const float* __restrict__ wi, const float* __restrict__ bi,
    const float* __restrict__ nwT, const float* __restrict__ nb1,
    float* __restrict__ state_out)
{
    __shared__ __attribute__((aligned(16))) float Y[TN * YS];      // 32.0 KB (smA aliased inside)
    __shared__ __attribute__((aligned(16))) float smP[TN * AP];    //  4.2 KB
    __shared__ __attribute__((aligned(16))) float sWaT[H2 * AP];   // 10.4 KB
    __shared__ __attribute__((aligned(16))) float sNwT[H2 * NWS];  // 21.6 KB
    __shared__ __attribute__((aligned(16))) float hs[TN * HSS];    //  8.0 KB
    __shared__ __attribute__((aligned(16))) float xs[TN * FD];
    __shared__ int sed[TN * KE];
    __shared__ int soff[TN];
    __shared__ int sdeg[TN];

    float* const smA = Y;              // smA dead before Y is written (phase C)

    int tid = threadIdx.x;
    int nb = blockIdx.x * TN;
    int c = tid;                       // output col for phase C
    int g = c & 3, o4 = c >> 2;

    // ---- stage: LDS weights, xs, edge metadata ----
    for (int idx = tid; idx < H2 * AP / 4; idx += 512)
        ((float4*)sWaT)[idx] = ((const float4*)WaT)[idx];
    for (int idx = tid; idx < H2 * NWS / 4; idx += 512)
        ((float4*)sNwT)[idx] = ((const float4*)nwT)[idx];
    if (tid < TN)
        ((float4*)xs)[tid] = ((const float4*)xrL)[nb + tid];
    if (fedge) {
        if (tid < TN * KE) sed[tid] = fedge[nb * KE + tid] - srcbase;
    } else {
        if (tid < TN) { soff[tid] = boffs[nb + tid]; sdeg[tid] = bdeg[nb + tid]; }
    }
    __syncthreads();

    // ---- phase A: gather + sum pre50 rows -> smA ----
    const float4* pre4 = (const float4*)preIn;
    for (int idx = tid; idx < TN * 13; idx += 512) {
        int n = idx / 13, q = idx - n * 13;
        float4 a = make_float4(0.f, 0.f, 0.f, 0.f);
        if (fedge) {
#pragma unroll
            for (int e = 0; e < KE; ++e) {
                int r = sed[KE * n + e];
                float4 v = pre4[r * 13 + q];
                a.x += v.x; a.y += v.y; a.z += v.z; a.w += v.w;
            }
        } else {
            int off = soff[n], d = sdeg[n];
            for (int e = 0; e < d; ++e) {
                int r = bnbr[off + e];
                float4 v = pre4[r * 13 + q];
                a.x += v.x; a.y += v.y; a.z += v.z; a.w += v.w;
            }
        }
        *(float4*)&smA[n * AP + 4 * q] = a;
    }
    __syncthreads();

    // ---- per-thread C bias/input weights (5 regs live across B) ----
    float b4c = 0.f, wx0 = 0.f, wx1 = 0.f, wx2 = 0.f, wx3 = 0.f;
    if (c < 400) {
        b4c = b4i[c];
        if (g == 1 || g == 2) {
            int off = ((g == 1) ? o4 : (100 + o4)) * 4;
            wx0 = wi[off + 0]; wx1 = wi[off + 1]; wx2 = wi[off + 2]; wx3 = wi[off + 3];
        }
    }

    // ---- phase B: p50 -> smP ----
    for (int idx = tid; idx < TN * H2; idx += 512) {
        int n = idx / H2, cc = idx - n * H2;
        float dgv = fedge ? 3.0f : (float)sdeg[n];
        float acc = pb1[cc] + dgv * b2p[cc];
        const float4* ar = (const float4*)&smA[n * AP];
        const float4* wr = (const float4*)&sWaT[cc * AP];
#pragma unroll
        for (int q = 0; q < 13; ++q) {
            float4 av = ar[q], wv = wr[q];
            acc = fmaf(av.x, wv.x, acc); acc = fmaf(av.y, wv.y, acc);
            acc = fmaf(av.z, wv.z, acc); acc = fmaf(av.w, wv.w, acc);
        }
        smP[n * AP + cc] = fmaxf(acc, 0.f);
    }
    __syncthreads();

    // ---- phase C: Y = b4 + P@W4i + xs@wx  (K-split: 24 + 24 + 2 tail) ----
    if (c < 400) {
        float acc[TN];
#pragma unroll
        for (int n = 0; n < TN; ++n) {
            float4 xv = *(const float4*)&xs[n * FD];
            float a = b4c;
            a = fmaf(xv.x, wx0, a); a = fmaf(xv.y, wx1, a);
            a = fmaf(xv.z, wx2, a); a = fmaf(xv.w, wx3, a);
            acc[n] = a;
        }
        float Wq[24];
#pragma unroll
        for (int k = 0; k < 24; ++k) Wq[k] = W4i[k * 400 + c];
#pragma unroll
        for (int n = 0; n < TN; ++n) {
            const float4* pr = (const float4*)&smP[n * AP];
            float a = acc[n];
#pragma unroll
            for (int q = 0; q < 6; ++q) {
                float4 pv = pr[q];
                a = fmaf(pv.x, Wq[4 * q + 0], a);
                a = fmaf(pv.y, Wq[4 * q + 1], a);
                a = fmaf(pv.z, Wq[4 * q + 2], a);
                a = fmaf(pv.w, Wq[4 * q + 3], a);
            }
            acc[n] = a;
        }
#pragma unroll
        for (int k = 0; k < 24; ++k) Wq[k] = W4i[(24 + k) * 400 + c];
        float Wt0 = W4i[48 * 400 + c];
        float Wt1 = W4i[49 * 400 + c];
#pragma unroll
        for (int n = 0; n < TN; ++n) {
            const float* prf = &smP[n * AP];
            const float4* pr = (const float4*)(prf + 24);
            float a = acc[n];
#pragma unroll
            for (int q = 0; q < 6; ++q) {
                float4 pv = pr[q];
                a = fmaf(pv.x, Wq[4 * q + 0], a);
                a = fmaf(pv.y, Wq[4 * q + 1], a);
                a = fmaf(pv.z, Wq[4 * q + 2], a);
                a = fmaf(pv.w, Wq[4 * q + 3], a);
            }
            a = fmaf(prf[48], Wt0, a);
            a = fmaf(prf[49], Wt1, a);
            Y[n * YS + c] = a;
        }
    }
    __syncthreads();

    // ---- GRU: flat (n,o) pairs across all 512 threads; fused state write ----
    for (int p = tid; p < TN * H; p += 512) {
        int n = p / H, o = p - n * H;
        float4 yv = *(const float4*)&Y[n * YS + 4 * o];
        float4 xv = *(const float4*)&xs[n * FD];
        float inn = bi[200 + o] + xv.x * wi[(200 + o) * 4 + 0]
                                + xv.y * wi[(200 + o) * 4 + 1]
                                + xv.z * wi[(200 + o) * 4 + 2]
                                + xv.w * wi[(200 + o) * 4 + 3];
        float r = sigmoidf_(yv.y);
        float z = sigmoidf_(yv.z);
        float t = tanhf_(inn + r * yv.w);
        float h = fmaf(z, yv.x - t, t);   // (1-z)t + z*m
        hs[n * HSS + o] = h;
        state_out[(size_t)(nb + n) * H + o] = h;
    }
    __syncthreads();

    // ---- phase D: next step's pre50 ----
    for (int idx = tid; idx < TN * H2; idx += 512) {
        int n = idx / H2, cc = idx - n * H2;
        float acc = nb1[cc];
        const float4* hr = (const float4*)&hs[n * HSS];
        const float4* wr = (const float4*)&sNwT[cc * NWS];
#pragma unroll
        for (int q = 0; q < 25; ++q) {
            float4 hv = hr[q], wv = wr[q];
            acc = fmaf(hv.x, wv.x, acc); acc = fmaf(hv.y, wv.y, acc);
            acc = fmaf(hv.z, wv.z, acc); acc = fmaf(hv.w, wv.w, acc);
        }
        preOut[(size_t)(nb + n) * AP + cc] = fmaxf(acc, 0.f);
    }
}

// ---------------------------------------------------------------------------
// xr = state @ proj_w + proj_b ; thread = (node, f)
// ---------------------------------------------------------------------------
__global__ __launch_bounds__(256) void proj_kernel(
    const float* __restrict__ state, const float* __restrict__ pw,
    const float* __restrict__ pb, float* __restrict__ xr)
{
    int t = blockIdx.x * 256 + threadIdx.x;
    if (t >= NT * FD) return;
    int node = t >> 2, f = t & 3;
    const float4* rp = (const float4*)(state + (size_t)node * H);
    float acc = pb[f];
    for (int i4 = 0; i4 < 25; ++i4) {
        float4 v = rp[i4];
        acc = fmaf(v.x, pw[(4 * i4 + 0) * 4 + f], acc);
        acc = fmaf(v.y, pw[(4 * i4 + 1) * 4 + f], acc);
        acc = fmaf(v.z, pw[(4 * i4 + 2) * 4 + f], acc);
        acc = fmaf(v.w, pw[(4 * i4 + 3) * 4 + f], acc);
    }
    xr[t] = acc;
}

// ---------------------------------------------------------------------------
__global__ void cls_kernel(const float* __restrict__ state,
                           const float* __restrict__ w1, const float* __restrict__ b1,
                           const float* __restrict__ w2, const float* __restrict__ b2,
                           float* __restrict__ pred)
{
    int n = blockIdx.x * blockDim.x + threadIdx.x;
    if (n >= NPL) return;
    float h[DM];
#pragma unroll
    for (int j = 0; j < DM; ++j) h[j] = b1[j];
    const float* sp = state + (size_t)n * H;
    for (int i = 0; i < H; ++i) {
        float s = sp[i];
#pragma unroll
        for (int j = 0; j < DM; ++j) h[j] = fmaf(s, w1[i * DM + j], h[j]);
    }
    float v = b2[0];
#pragma unroll
    for (int j = 0; j < DM; ++j) v = fmaf(fmaxf(h[j], 0.f), w2[j], v);
    pred[n] = sigmoidf_(v);
}

// ---------------------------------------------------------------------------
__global__ void gate_kernel(const float* __restrict__ x, const int* __restrict__ src,
                            float* __restrict__ pred, int l)
{
    int j = blockIdx.x * blockDim.x + threadIdx.x;
    if (j >= NPL) return;
    int e0 = (l - 1) * EPL + KE * j;
    int dg = l * NPL + j;
    float v0 = pred[src[e0 + 0]];
    float v1 = pred[src[e0 + 1]];
    float v2 = pred[src[e0 + 2]];
    const float invT = 100.0f;
    float mx = fmaxf(v0, fmaxf(v1, v2));
    float e0x = __expf((v0 - mx) * invT);
    float e1x = __expf((v1 - mx) * invT);
    float e2x = __expf((v2 - mx) * invT);
    float smax = (e0x * v0 + e1x * v1 + e2x * v2) / (e0x + e1x + e2x);
    float mn = fminf(v0, fminf(v1, v2));
    float f0 = __expf((mn - v0) * invT);
    float f1 = __expf((mn - v1) * invT);
    float f2 = __expf((mn - v2) * invT);
    float smin = (f0 * v0 + f1 * v1 + f2 * v2) / (f0 + f1 + f2);
    float am = x[(size_t)dg * FD + 1];
    float om = x[(size_t)dg * FD + 2];
    float nm = x[(size_t)dg * FD + 3];
    pred[dg] = am * smin + om * smax + nm * (3.f - (v0 + v1 + v2));
}

__global__ void copy_kernel(const float* __restrict__ pred, float* __restrict__ out)
{
    int j = blockIdx.x * blockDim.x + threadIdx.x;
    if (j < NPL) out[j] = pred[(NLV - 1) * NPL + j];
}

// ---------------------------------------------------------------------------
extern "C" void kernel_launch(void* const* d_in, const int* in_sizes, int n_in,
                              void* d_out, int out_size, void* d_ws, size_t ws_size,
                              hipStream_t stream)
{
    const float* x        = (const float*)d_in[0];
    const float* fpre_w1  = (const float*)d_in[1];
    const float* fpre_b1  = (const float*)d_in[2];
    const float* fpre_w2  = (const float*)d_in[3];
    const float* fpre_b2  = (const float*)d_in[4];
    const float* fpost_w1 = (const float*)d_in[5];
    const float* fpost_b1 = (const float*)d_in[6];
    const float* fpost_w2 = (const float*)d_in[7];
    const float* fpost_b2 = (const float*)d_in[8];
    const float* bpre_w1  = (const float*)d_in[9];
    const float* bpre_b1  = (const float*)d_in[10];
    const float* bpre_w2  = (const float*)d_in[11];
    const float* bpre_b2  = (const float*)d_in[12];
    const float* bpost_w1 = (const float*)d_in[13];
    const float* bpost_b1 = (const float*)d_in[14];
    const float* bpost_w2 = (const float*)d_in[15];
    const float* bpost_b2 = (const float*)d_in[16];
    const float* gruf_wi  = (const float*)d_in[17];
    const float* gruf_wh  = (const float*)d_in[18];
    const float* gruf_bi  = (const float*)d_in[19];
    const float* gruf_bh  = (const float*)d_in[20];
    const float* grub_wi  = (const float*)d_in[21];
    const float* grub_wh  = (const float*)d_in[22];
    const float* grub_bi  = (const float*)d_in[23];
    const float* grub_bh  = (const float*)d_in[24];
    const float* proj_w   = (const float*)d_in[25];
    const float* proj_b   = (const float*)d_in[26];
    const float* cls_w1   = (const float*)d_in[27];
    const float* cls_b1   = (const float*)d_in[28];
    const float* cls_w2   = (const float*)d_in[29];
    const float* cls_b2   = (const float*)d_in[30];
    const int*   src      = (const int*)d_in[31];
    const int*   dst      = (const int*)d_in[32];
    float* out = (float*)d_out;

    size_t o = 0;
    auto carve = [&](size_t nbytes) -> void* {
        void* p = (char*)d_ws + o;
        o += (nbytes + 255) & ~(size_t)255;
        return p;
    };
    float* state = (float*)carve((size_t)NT * H * 4);        // 48 MB
    float* xr    = (float*)carve((size_t)NT * FD * 4);
    float* pred  = (float*)carve((size_t)NT * 4);
    float* pre0  = (float*)carve((size_t)NPL * AP * 4);      // 2.08 MB
    float* pre1  = (float*)carve((size_t)NPL * AP * 4);
    int*   counts= (int*)carve((size_t)11 * NPL * 4);
    int*   cursor= (int*)carve((size_t)11 * NPL * 4);
    int*   offs  = (int*)carve((size_t)11 * NPL * 4);
    int*   nbrb  = (int*)carve((size_t)NE * 4);
    float* WaTF  = (float*)carve(H2 * AP * 4);
    float* b2pF  = (float*)carve(64 * 4);
    float* W4iF  = (float*)carve(H2 * 400 * 4);
    float* b4iF  = (float*)carve(400 * 4);
    float* nwTF  = (float*)carve(H2 * NWS * 4);
    float* WaTB  = (float*)carve(H2 * AP * 4);
    float* b2pB  = (float*)carve(64 * 4);
    float* W4iB  = (float*)carve(H2 * 400 * 4);
    float* b4iB  = (float*)carve(400 * 4);
    float* nwTB  = (float*)carve(H2 * NWS * 4);

    // zero counts AND cursor INCLUDING alignment padding between them
    hipMemsetAsync(counts, 0, (size_t)((char*)offs - (char*)counts), stream);

    fold_kernel<<<(2 * 28350 + 255) / 256, 256, 0, stream>>>(
        fpre_w2, fpre_b2, fpost_w1, fpost_w2, fpost_b2, gruf_wh, gruf_bh, gruf_bi, fpre_w1,
        bpre_w2, bpre_b2, bpost_w1, bpost_w2, bpost_b2, grub_wh, grub_bh, grub_bi, bpre_w1,
        WaTF, b2pF, W4iF, b4iF, nwTF,
        WaTB, b2pB, W4iB, b4iB, nwTB);
    csr_count<<<(NE + 255) / 256, 256, 0, stream>>>(src, counts);
    csr_scan<<<11, 256, 0, stream>>>(counts, offs);
    csr_fill<<<(NE + 255) / 256, 256, 0, stream>>>(src, dst, offs, cursor, nbrb);
    pre_init<<<(NPL * AP + 255) / 256, 256, 0, stream>>>(fpre_b1, pre0, pre1);

    float* preBuf[2] = { pre0, pre1 };
    int pb = 0;
    const int k3Grid = NPL / TN;   // 500

    for (int r = 0; r < 2; ++r) {
        const float* xr_use;
        if (r == 0) {
            xr_use = x;
        } else {
            proj_kernel<<<(NT * FD + 255) / 256, 256, 0, stream>>>(state, proj_w, proj_b, xr);
            xr_use = xr;
        }
        // forward levels 1..11
        for (int l = 1; l < NLV; ++l) {
            bool lastf = (l == NLV - 1);
            k3_kernel<<<k3Grid, 512, 0, stream>>>(
                preBuf[pb], preBuf[pb ^ 1],
                src + (size_t)(l - 1) * EPL, (l - 1) * NPL,
                nullptr, nullptr, nullptr,
                xr_use + (size_t)l * NPL * FD,
                WaTF, b2pF, fpost_b1, W4iF, b4iF, gruf_wi, gruf_bi,
                lastf ? nwTB : nwTF, lastf ? bpre_b1 : fpre_b1,
                state + (size_t)l * NPL * H);
            pb ^= 1;
        }
        // backward levels 10..0
        for (int f = NLV - 2; f >= 0; --f) {
            bool lastb = (f == 0);
            k3_kernel<<<k3Grid, 512, 0, stream>>>(
                preBuf[pb], preBuf[pb ^ 1],
                nullptr, 0,
                offs + (size_t)f * NPL, counts + (size_t)f * NPL, nbrb + (size_t)f * EPL,
                xr_use + (size_t)f * NPL * FD,
                WaTB, b2pB, bpost_b1, W4iB, b4iB, grub_wi, grub_bi,
                lastb ? nwTF : nwTB, lastb ? fpre_b1 : bpre_b1,
                state + (size_t)f * NPL * H);
            pb ^= 1;
        }
    }

    cls_kernel<<<(NPL + 255) / 256, 256, 0, stream>>>(state, cls_w1, cls_b1, cls_w2, cls_b2, pred);
    for (int l = 1; l < NLV; ++l)
        gate_kernel<<<(NPL + 255) / 256, 256, 0, stream>>>(x, src, pred, l);
    copy_kernel<<<(NPL + 255) / 256, 256, 0, stream>>>(pred, out);
}